// Round 11
// baseline (175.333 us; speedup 1.0000x reference)
//
#include <hip/hip_runtime.h>
#include <hip/hip_bf16.h>

// attention_84464826843938: additive-attention pooling, MI355X (gfx950)
//
// R11: A-delivery experiment. Cross-round invariant: delivered A-bytes
// (268MB) / time = ~3.2 TB/s for R2/R6/R7/R10 regardless of staging scheme.
// Hypothesis: 256B-per-row segmented A-requests run at half the 6.3 TB/s
// 1KB-contiguous ceiling. Fix: BK=256 super-steps; wave wid loads rows
// [wid*8,+8), lane l reads row[l*4..+4] -> each instr = 1KB of ONE row
// (the float4-copy pattern), issued a full super-step ahead into regs;
// cvt->frg (2x32KB dbuf, XOR-swizzled b64 writes) once per super at sub3.
// Everything else IDENTICAL to R10: BM=64/BN=256 slice-major, 512thr/8waves,
// wave 64rx32c, B reg-prefetch bA/bB alternating, counted vmcnt
// (derived 12/12/4/4 per sub-step; tail 4/4/4/0), setprio MFMA, epilogue.

#define B_ 256
#define R_ 64
#define F_ 2048
#define H_ 512
#define DIM_ 512

typedef short bf16x8 __attribute__((ext_vector_type(8)));
typedef float f32x4 __attribute__((ext_vector_type(4)));

__device__ __forceinline__ ushort f2bf(float x) {
  __hip_bfloat16 h = __float2bfloat16(x);
  return __builtin_bit_cast(ushort, h);
}

__device__ __forceinline__ uint2 pack4(float4 x) {
  uint2 r;
  r.x = (uint)f2bf(x.x) | ((uint)f2bf(x.y) << 16);
  r.y = (uint)f2bf(x.z) | ((uint)f2bf(x.w) << 16);
  return r;
}

// blocks [0,4096): wpack[((kt*32+ctg)*64 + g*16 + c)*8 + i] = bf16(W_w[kt*32+g*8+i][ctg*16+c])
// blocks [4096,4352): p'[b][d] = prev[b]@W2_w[:,d] + W2_b[d] + W_b[d]
__global__ __launch_bounds__(256) void setup_k(const float* __restrict__ Ww,
                                               ushort* __restrict__ wpack,
                                               const float* __restrict__ prev,
                                               const float* __restrict__ W2w,
                                               const float* __restrict__ W2b,
                                               const float* __restrict__ Wb,
                                               float* __restrict__ pprime) {
  __shared__ float lprev[8][H_];
  if (blockIdx.x < 4096) {
    int idx = blockIdx.x * 256 + threadIdx.x;
    float v = Ww[idx];
    int k = idx >> 9;
    int d = idx & 511;
    int kt = k >> 5, kr = k & 31;
    int g = kr >> 3, i = kr & 7;
    int ctg = d >> 4, c = d & 15;
    size_t dst = ((size_t)((kt * 32 + ctg) * 64 + g * 16 + c)) * 8 + (size_t)i;
    wpack[dst] = f2bf(v);
    return;
  }
  int pb = blockIdx.x - 4096;
  int bg = pb >> 3;
  int d0 = (pb & 7) * 64;
  int t = threadIdx.x;
  const float4* src = reinterpret_cast<const float4*>(prev + (size_t)bg * 8 * H_);
  float4* dst = reinterpret_cast<float4*>(&lprev[0][0]);
  for (int i = t; i < 8 * H_ / 4; i += 256) dst[i] = src[i];
  __syncthreads();
  int d = d0 + (t & 63);
  int bq = t >> 6;
  float a0 = 0.f, a1 = 0.f;
  #pragma unroll 8
  for (int h = 0; h < H_; ++h) {
    float wv = W2w[h * DIM_ + d];
    a0 += lprev[bq][h] * wv;
    a1 += lprev[bq + 4][h] * wv;
  }
  float bias = W2b[d] + Wb[d];
  pprime[(size_t)(bg * 8 + bq) * DIM_ + d] = a0 + bias;
  pprime[(size_t)(bg * 8 + bq + 4) * DIM_ + d] = a1 + bias;
}

__device__ __forceinline__ float fast_tanh(float x) {
  float e = __expf(2.f * x);
  return 1.f - 2.f / (e + 1.f);
}

// sp[b*2+slice][r] = sum_{d in slice's 256 cols} tanh(c[b][r][d]+p'[b][d])*W3[d]
__global__ __launch_bounds__(512, 4) void score_k(const float* __restrict__ feat,
                                                  const ushort* __restrict__ wpack,
                                                  const float* __restrict__ pprime,
                                                  const float* __restrict__ W3,
                                                  float* __restrict__ sp) {
  int slice = blockIdx.x >> 8;          // slice-major: both slices of b same XCD
  int b = blockIdx.x & 255;
  int t = threadIdx.x;
  int wid = t >> 6;                     // 8 waves; wave owns cols [wid*32,+32)
  int l = t & 63;
  int l15 = l & 15, g = l >> 4;
  const float* featB = feat + (size_t)b * R_ * F_;

  // frg[buf][kc*64 + (row ^ (kc&15))] = bf16 A[row][k = S*256 + kc*8 .. +8]
  __shared__ uint4 frg[2][2048];        // 2 x 32 KB super-tile double buffer
  __shared__ float lds_part[8][R_];

  f32x4 acc[4][2];
  #pragma unroll
  for (int rt = 0; rt < 4; ++rt)
    #pragma unroll
    for (int ct = 0; ct < 2; ++ct)
      acc[rt][ct] = (f32x4){0.f, 0.f, 0.f, 0.f};

  // ---- A-load geometry: wave wid rows [wid*8,+8); lane l reads row[l*4..+4]
  // => one instr = 64 lanes x 16B = 1KB of ONE row (full-coalesced pattern).
  const float* abase = featB + (size_t)(wid * 8) * F_ + (size_t)(l * 4);
  float4 rA[8];

  // ---- cvt geometry: lane l -> kc = l>>1, 8B-half = l&1; writes its 8 rows.
  int kcl = l >> 1;
  int whalf = l & 1;

  // ---- B pointer: frag(kt,s,ct) at wp + kt*32768 + s*16384 + ct*512 (ushorts)
  const ushort* wp = wpack + (size_t)(slice * 16 + wid * 2) * 512 + (size_t)l * 8;

#define LOADA(S) do {                                              \
    const float* ap_ = abase + (size_t)(S) * 256;                  \
    _Pragma("unroll")                                              \
    for (int j_ = 0; j_ < 8; ++j_)                                 \
      rA[j_] = *reinterpret_cast<const float4*>(ap_ + (size_t)j_ * F_); \
  } while (0)

#define LOADB(dst, kt) do {                                        \
    const ushort* wpk_ = wp + (size_t)(kt) * 32768;                \
    dst[0][0] = *reinterpret_cast<const uint4*>(wpk_);             \
    dst[0][1] = *reinterpret_cast<const uint4*>(wpk_ + 512);       \
    dst[1][0] = *reinterpret_cast<const uint4*>(wpk_ + 16384);     \
    dst[1][1] = *reinterpret_cast<const uint4*>(wpk_ + 16384 + 512); \
  } while (0)

#define CVT(fb) do {                                               \
    _Pragma("unroll")                                              \
    for (int j_ = 0; j_ < 8; ++j_) {                               \
      int row_ = wid * 8 + j_;                                     \
      int idx_ = kcl * 64 + (row_ ^ (kcl & 15));                   \
      uint2 pk_ = pack4(rA[j_]);                                   \
      *(reinterpret_cast<uint2*>(&frg[fb][idx_]) + whalf) = pk_;   \
    }                                                              \
  } while (0)

#define MFMA_SUB(fb, tt, BSET) do {                                \
    _Pragma("unroll")                                              \
    for (int s_ = 0; s_ < 2; ++s_) {                               \
      int kcg_ = (tt) * 8 + s_ * 4 + g;                            \
      bf16x8 af_[4];                                               \
      _Pragma("unroll")                                            \
      for (int rt_ = 0; rt_ < 4; ++rt_)                            \
        af_[rt_] = __builtin_bit_cast(bf16x8,                      \
            frg[fb][kcg_ * 64 + ((rt_ * 16 + l15) ^ (kcg_ & 15))]); \
      _Pragma("unroll")                                            \
      for (int ct_ = 0; ct_ < 2; ++ct_) {                          \
        bf16x8 bv_ = __builtin_bit_cast(bf16x8, BSET[s_][ct_]);    \
        _Pragma("unroll")                                          \
        for (int rt_ = 0; rt_ < 4; ++rt_)                          \
          acc[rt_][ct_] = __builtin_amdgcn_mfma_f32_16x16x32_bf16( \
              af_[rt_], bv_, acc[rt_][ct_], 0, 0, 0);              \
      }                                                            \
    }                                                              \
  } while (0)

#define BARRIER_VM(N) do {                                         \
    asm volatile("s_waitcnt vmcnt(" #N ") lgkmcnt(0)" ::: "memory"); \
    __builtin_amdgcn_s_barrier();                                  \
    asm volatile("" ::: "memory");                                 \
  } while (0)

  uint4 bA[2][2], bB[2][2];
  // prologue: A(0) + B(0); drain A(0) (keep B(0):4); cvt(0) -> frg[0]
  LOADA(0);
  LOADB(bA, 0);
  asm volatile("s_waitcnt vmcnt(4)" ::: "memory");
  CVT(0);

  // super-steps S=0..6 uniform; S=7 peeled tail.
  // Per sub-step: {issue loads} -> vmcnt+lgkm+barrier -> MFMA (+cvt at sub3).
  // Queues (per wave, oldest->newest), derived:
  //  sub0: [B(4S):4, B(4S+1):4, A(S+1):8]      -> vmcnt(12)
  //  sub1: [B(4S+1):4, A(S+1):8, B(4S+2):4]    -> vmcnt(12)
  //  sub2: [A(S+1):8, B(4S+2):4, B(4S+3):4]    -> vmcnt(4)  (drains A too)
  //  sub3: [B(4S+3):4, B(4S+4):4]              -> vmcnt(4); cvt(S+1)
  for (int S = 0; S < 7; ++S) {
    int fb = S & 1;
    // sub0
    LOADB(bB, S * 4 + 1);
    LOADA(S + 1);
    BARRIER_VM(12);
    __builtin_amdgcn_s_setprio(1);
    MFMA_SUB(fb, 0, bA);
    __builtin_amdgcn_s_setprio(0);
    // sub1
    LOADB(bA, S * 4 + 2);
    BARRIER_VM(12);
    __builtin_amdgcn_s_setprio(1);
    MFMA_SUB(fb, 1, bB);
    __builtin_amdgcn_s_setprio(0);
    // sub2
    LOADB(bB, S * 4 + 3);
    BARRIER_VM(4);
    __builtin_amdgcn_s_setprio(1);
    MFMA_SUB(fb, 2, bA);
    __builtin_amdgcn_s_setprio(0);
    // sub3: cvt(S+1) into the other frg buffer (its last readers were super
    // S-1 sub3, >=4 barriers ago)
    LOADB(bA, S * 4 + 4);
    BARRIER_VM(4);
    CVT(fb ^ 1);
    __builtin_amdgcn_s_setprio(1);
    MFMA_SUB(fb, 3, bB);
    __builtin_amdgcn_s_setprio(0);
  }
  // S=7 tail (frg[1], no A loads, no cvt): queues -> 4/4/4/0
  LOADB(bB, 29);
  BARRIER_VM(4);
  __builtin_amdgcn_s_setprio(1);
  MFMA_SUB(1, 0, bA);
  __builtin_amdgcn_s_setprio(0);
  LOADB(bA, 30);
  BARRIER_VM(4);
  __builtin_amdgcn_s_setprio(1);
  MFMA_SUB(1, 1, bB);
  __builtin_amdgcn_s_setprio(0);
  LOADB(bB, 31);
  BARRIER_VM(4);
  __builtin_amdgcn_s_setprio(1);
  MFMA_SUB(1, 2, bA);
  __builtin_amdgcn_s_setprio(0);
  BARRIER_VM(0);
  __builtin_amdgcn_s_setprio(1);
  MFMA_SUB(1, 3, bB);
  __builtin_amdgcn_s_setprio(0);

#undef LOADA
#undef LOADB
#undef CVT
#undef MFMA_SUB
#undef BARRIER_VM

  // epilogue: tanh + W3 dot in registers
  // acc[rt][ct][j] = c[row = rt*16 + g*4 + j][col = slice*256 + wid*32 + ct*16 + l15]
  float pp[2], w3v[2];
  #pragma unroll
  for (int ct = 0; ct < 2; ++ct) {
    int col = slice * 256 + wid * 32 + ct * 16 + l15;
    pp[ct] = pprime[b * DIM_ + col];
    w3v[ct] = W3[col];
  }
  #pragma unroll
  for (int rt = 0; rt < 4; ++rt) {
    #pragma unroll
    for (int j = 0; j < 4; ++j) {
      float v = fast_tanh(acc[rt][0][j] + pp[0]) * w3v[0]
              + fast_tanh(acc[rt][1][j] + pp[1]) * w3v[1];
      v += __shfl_xor(v, 1);
      v += __shfl_xor(v, 2);
      v += __shfl_xor(v, 4);
      v += __shfl_xor(v, 8);
      if (l15 == 0) lds_part[wid][rt * 16 + g * 4 + j] = v;
    }
  }
  __syncthreads();

  if (t < R_) {
    float s = 0.f;
    #pragma unroll
    for (int w = 0; w < 8; ++w) s += lds_part[w][t];
    sp[((size_t)b * 2 + slice) * R_ + t] = s;
  }
}

// softmax + weighted sum: grid = B*4, 256 thr, 512 f per block
__global__ __launch_bounds__(256) void wsum_k(const float* __restrict__ feat,
                                              const float* __restrict__ sp,
                                              float* __restrict__ out) {
  int b = blockIdx.x >> 2;
  int f0 = (blockIdx.x & 3) * 512;
  int t = threadIdx.x;
  __shared__ float lds_aw[R_];

  if (t < R_) {
    float s = sp[((size_t)b * 2 + 0) * R_ + t] + sp[((size_t)b * 2 + 1) * R_ + t];
    float m = s;
    #pragma unroll
    for (int off = 32; off >= 1; off >>= 1) m = fmaxf(m, __shfl_xor(m, off));
    float e = __expf(s - m);
    float su = e;
    #pragma unroll
    for (int off = 32; off >= 1; off >>= 1) su += __shfl_xor(su, off);
    lds_aw[t] = e / su;
  }
  __syncthreads();

  const float* fp = feat + (size_t)b * R_ * F_ + f0 + t * 2;
  float qx = 0.f, qy = 0.f;
  #pragma unroll 8
  for (int r = 0; r < R_; ++r) {
    float a = lds_aw[r];
    float2 v = *reinterpret_cast<const float2*>(fp + (size_t)r * F_);
    qx += a * v.x;
    qy += a * v.y;
  }
  *reinterpret_cast<float2*>(out + (size_t)b * F_ + f0 + t * 2) = (float2){qx, qy};
}

extern "C" void kernel_launch(void* const* d_in, const int* in_sizes, int n_in,
                              void* d_out, int out_size, void* d_ws, size_t ws_size,
                              hipStream_t stream) {
  const float* feat = (const float*)d_in[0];   // [B,R,F]
  const float* prev = (const float*)d_in[1];   // [B,H]
  const float* Ww   = (const float*)d_in[2];   // [F,DIM]
  const float* Wb   = (const float*)d_in[3];   // [DIM]
  const float* W2w  = (const float*)d_in[4];   // [H,DIM]
  const float* W2b  = (const float*)d_in[5];   // [DIM]
  const float* W3w  = (const float*)d_in[6];   // [DIM,1]
  // d_in[7] = W3_b: cancels in softmax
  float* out = (float*)d_out;

  ushort* wpack  = (ushort*)d_ws;                                          // 2 MB
  float*  pprime = (float*)((char*)d_ws + (size_t)F_ * DIM_ * 2);          // 512 KB
  float*  sp     = (float*)((char*)d_ws + (size_t)F_ * DIM_ * 2
                                        + (size_t)B_ * DIM_ * 4);          // 128 KB

  setup_k<<<4096 + 256, 256, 0, stream>>>(Ww, wpack, prev, W2w, W2b, Wb, pprime);
  score_k<<<B_ * 2, 512, 0, stream>>>(feat, wpack, pprime, W3w, sp);
  wsum_k<<<B_ * 4, 256, 0, stream>>>(feat, sp, out);
}

// Round 12
// 117.679 us; speedup vs baseline: 1.4899x; 1.4899x over previous
//
#include <hip/hip_runtime.h>
#include <hip/hip_bf16.h>

// attention_84464826843938: additive-attention pooling, MI355X (gfx950)
//
// R12: m201-style double-barrier phase pipeline on R10 geometry.
//  R11 postmortem: reg-held super-tile spilled (WRITE_SIZE 53MB scratch).
//  R10 accounting: region-pair 2560cyc vs LDS ~1500 + L2 ~1150 + MFMA 320 —
//  components serialize. Fix = m201 phases: per BK=64 region, 2 phases of
//  {ds_read frags | issue next-region globals | s_barrier | lgkm(0)+sched_bar |
//   setprio MFMA x8 setprio | s_barrier}. A-staging = reg-stage fp32 (issued a
//  full region early, T14) + cvt + ds_write_b64 into XOR(row^kc)-swizzled bf16
//  frg dbuf — no DMA ring (-80KB LDS traffic/region/block). No manual vmcnt
//  (compiler tracks reg waits). Named even/odd reg sets (rule #20).
//  Geometry unchanged: BM=64 BN=256 BK=64, 512thr/8 waves, wave 64rx32c,
//  grid 512 slice-major (2 blocks/CU), B-frags from packed global.

#define B_ 256
#define R_ 64
#define F_ 2048
#define H_ 512
#define DIM_ 512

typedef short bf16x8 __attribute__((ext_vector_type(8)));
typedef float f32x4 __attribute__((ext_vector_type(4)));

__device__ __forceinline__ ushort f2bf(float x) {
  __hip_bfloat16 h = __float2bfloat16(x);
  return __builtin_bit_cast(ushort, h);
}

__device__ __forceinline__ uint2 pack4(float4 x) {
  uint2 r;
  r.x = (uint)f2bf(x.x) | ((uint)f2bf(x.y) << 16);
  r.y = (uint)f2bf(x.z) | ((uint)f2bf(x.w) << 16);
  return r;
}

// blocks [0,4096): wpack[((kt*32+ctg)*64 + g*16 + c)*8 + i] = bf16(W_w[kt*32+g*8+i][ctg*16+c])
// blocks [4096,4352): p'[b][d] = prev[b]@W2_w[:,d] + W2_b[d] + W_b[d]
__global__ __launch_bounds__(256) void setup_k(const float* __restrict__ Ww,
                                               ushort* __restrict__ wpack,
                                               const float* __restrict__ prev,
                                               const float* __restrict__ W2w,
                                               const float* __restrict__ W2b,
                                               const float* __restrict__ Wb,
                                               float* __restrict__ pprime) {
  __shared__ float lprev[8][H_];
  if (blockIdx.x < 4096) {
    int idx = blockIdx.x * 256 + threadIdx.x;
    float v = Ww[idx];
    int k = idx >> 9;
    int d = idx & 511;
    int kt = k >> 5, kr = k & 31;
    int g = kr >> 3, i = kr & 7;
    int ctg = d >> 4, c = d & 15;
    size_t dst = ((size_t)((kt * 32 + ctg) * 64 + g * 16 + c)) * 8 + (size_t)i;
    wpack[dst] = f2bf(v);
    return;
  }
  int pb = blockIdx.x - 4096;
  int bg = pb >> 3;
  int d0 = (pb & 7) * 64;
  int t = threadIdx.x;
  const float4* src = reinterpret_cast<const float4*>(prev + (size_t)bg * 8 * H_);
  float4* dst = reinterpret_cast<float4*>(&lprev[0][0]);
  for (int i = t; i < 8 * H_ / 4; i += 256) dst[i] = src[i];
  __syncthreads();
  int d = d0 + (t & 63);
  int bq = t >> 6;
  float a0 = 0.f, a1 = 0.f;
  #pragma unroll 8
  for (int h = 0; h < H_; ++h) {
    float wv = W2w[h * DIM_ + d];
    a0 += lprev[bq][h] * wv;
    a1 += lprev[bq + 4][h] * wv;
  }
  float bias = W2b[d] + Wb[d];
  pprime[(size_t)(bg * 8 + bq) * DIM_ + d] = a0 + bias;
  pprime[(size_t)(bg * 8 + bq + 4) * DIM_ + d] = a1 + bias;
}

__device__ __forceinline__ float fast_tanh(float x) {
  float e = __expf(2.f * x);
  return 1.f - 2.f / (e + 1.f);
}

// sp[b*2+slice][r] = sum_{d in slice's 256 cols} tanh(c[b][r][d]+p'[b][d])*W3[d]
__global__ __launch_bounds__(512, 4) void score_k(const float* __restrict__ feat,
                                                  const ushort* __restrict__ wpack,
                                                  const float* __restrict__ pprime,
                                                  const float* __restrict__ W3,
                                                  float* __restrict__ sp) {
  int slice = blockIdx.x >> 8;          // slice-major: both slices of b same XCD
  int b = blockIdx.x & 255;
  int t = threadIdx.x;
  int wid = t >> 6;                     // 8 waves; wave owns cols [wid*32,+32)
  int l = t & 63;
  int l15 = l & 15, g = l >> 4;
  const float* featB = feat + (size_t)b * R_ * F_;

  // frg[buf][kc*64 + (row ^ kc)] = bf16 A[row][k = kt*64 + kc*8 .. +8]
  __shared__ uint4 frg[2][512];         // 2 x 8 KB double buffer
  __shared__ float lds_part[8][R_];

  f32x4 acc[4][2];
  #pragma unroll
  for (int rt = 0; rt < 4; ++rt)
    #pragma unroll
    for (int ct = 0; ct < 2; ++ct)
      acc[rt][ct] = (f32x4){0.f, 0.f, 0.f, 0.f};

  // ---- A staging: thread t covers rows r0=t>>4 and r0+32, float4 chunk c4=t&15
  int r0 = t >> 4;                      // 0..31
  int c4 = t & 15;
  const float* ga0 = featB + (size_t)r0 * F_ + (size_t)(c4 * 4);
  const float* ga1 = featB + (size_t)(r0 + 32) * F_ + (size_t)(c4 * 4);
  int kcw = c4 >> 1, half = c4 & 1;     // dest: frag chunk kcw, 8B-half
  int wi0 = kcw * 64 + (r0 ^ kcw);
  int wi1 = kcw * 64 + ((r0 + 32) ^ kcw);

  // ---- B pointer: frag(kt,s,ct) at wp + kt*32768 + s*16384 + ct*512 (ushorts)
  const ushort* wp = wpack + (size_t)(slice * 16 + wid * 2) * 512 + (size_t)l * 8;

#define LOADB(dst, kt) do {                                          \
    const ushort* wpk_ = wp + (size_t)(kt) * 32768;                  \
    dst[0][0] = *reinterpret_cast<const uint4*>(wpk_);               \
    dst[0][1] = *reinterpret_cast<const uint4*>(wpk_ + 512);         \
    dst[1][0] = *reinterpret_cast<const uint4*>(wpk_ + 16384);       \
    dst[1][1] = *reinterpret_cast<const uint4*>(wpk_ + 16384 + 512); \
  } while (0)

#define CVTW(fb, ASET) do {                                          \
    uint2* d0_ = reinterpret_cast<uint2*>(&frg[fb][wi0]);            \
    d0_[half] = pack4(ASET[0]);                                      \
    uint2* d1_ = reinterpret_cast<uint2*>(&frg[fb][wi1]);            \
    d1_[half] = pack4(ASET[1]);                                      \
  } while (0)

#define MFMA8(AF, BSET, s_) do {                                     \
    _Pragma("unroll")                                                \
    for (int ct_ = 0; ct_ < 2; ++ct_) {                              \
      bf16x8 bv_ = __builtin_bit_cast(bf16x8, BSET[s_][ct_]);        \
      _Pragma("unroll")                                              \
      for (int rt_ = 0; rt_ < 4; ++rt_)                              \
        acc[rt_][ct_] = __builtin_amdgcn_mfma_f32_16x16x32_bf16(     \
            __builtin_bit_cast(bf16x8, AF[rt_]), bv_, acc[rt_][ct_], 0, 0, 0); \
    }                                                                \
  } while (0)

#define FENCE() asm volatile("" ::: "memory")
#define BAR() do { FENCE(); __builtin_amdgcn_s_barrier(); FENCE(); } while (0)
#define LGKM0() do {                                                 \
    asm volatile("s_waitcnt lgkmcnt(0)" ::: "memory");               \
    __builtin_amdgcn_sched_barrier(0);                               \
  } while (0)

  // REGION(kt): P0 {ds_read s0 | issue A(kt+2),B(kt+1) | bar | lgkm | MFMA s0 | bar}
  //             P1 {ds_read s1 | cvt A(kt+1)->frg[(kt+1)&1] | bar | lgkm | MFMA s1 | bar}
#define REGION(kt, aCvt, aFill, bUse, bFill) do {                    \
    uint4 af0_[4], af1_[4];                                          \
    _Pragma("unroll")                                                \
    for (int rt_ = 0; rt_ < 4; ++rt_)                                \
      af0_[rt_] = frg[(kt) & 1][g * 64 + ((rt_ * 16 + l15) ^ g)];    \
    if ((kt) < 30) {                                                 \
      aFill[0] = *reinterpret_cast<const float4*>(ga0 + ((kt) + 2) * 64); \
      aFill[1] = *reinterpret_cast<const float4*>(ga1 + ((kt) + 2) * 64); \
    }                                                                \
    if ((kt) < 31) LOADB(bFill, (kt) + 1);                           \
    BAR();                                                           \
    LGKM0();                                                         \
    __builtin_amdgcn_s_setprio(1);                                   \
    MFMA8(af0_, bUse, 0);                                            \
    __builtin_amdgcn_s_setprio(0);                                   \
    BAR();                                                           \
    _Pragma("unroll")                                                \
    for (int rt_ = 0; rt_ < 4; ++rt_) {                              \
      int kc_ = 4 + g;                                               \
      af1_[rt_] = frg[(kt) & 1][kc_ * 64 + ((rt_ * 16 + l15) ^ kc_)]; \
    }                                                                \
    if ((kt) < 31) CVTW(((kt) + 1) & 1, aCvt);                       \
    BAR();                                                           \
    LGKM0();                                                         \
    __builtin_amdgcn_s_setprio(1);                                   \
    MFMA8(af1_, bUse, 1);                                            \
    __builtin_amdgcn_s_setprio(0);                                   \
    BAR();                                                           \
  } while (0)

  float4 aS0[2], aS1[2];
  uint4 b0[2][2], b1[2][2];

  // prologue: A(0)->aS0, B(0)->b0; cvt A(0)->frg[0]; A(1)->aS1; publish
  aS0[0] = *reinterpret_cast<const float4*>(ga0);
  aS0[1] = *reinterpret_cast<const float4*>(ga1);
  LOADB(b0, 0);
  CVTW(0, aS0);
  aS1[0] = *reinterpret_cast<const float4*>(ga0 + 64);
  aS1[1] = *reinterpret_cast<const float4*>(ga1 + 64);
  LGKM0();
  BAR();

  for (int kt = 0; kt < 32; kt += 2) {
    REGION(kt, aS1, aS0, b0, b1);       // cvt A(kt+1)=aS1, fill A(kt+2)->aS0, use B set0, fill set1
    REGION(kt + 1, aS0, aS1, b1, b0);
  }

#undef LOADB
#undef CVTW
#undef MFMA8
#undef REGION
#undef BAR
#undef LGKM0
#undef FENCE

  // epilogue: tanh + W3 dot in registers
  // acc[rt][ct][j] = c[row = rt*16 + g*4 + j][col = slice*256 + wid*32 + ct*16 + l15]
  float pp[2], w3v[2];
  #pragma unroll
  for (int ct = 0; ct < 2; ++ct) {
    int col = slice * 256 + wid * 32 + ct * 16 + l15;
    pp[ct] = pprime[b * DIM_ + col];
    w3v[ct] = W3[col];
  }
  #pragma unroll
  for (int rt = 0; rt < 4; ++rt) {
    #pragma unroll
    for (int j = 0; j < 4; ++j) {
      float v = fast_tanh(acc[rt][0][j] + pp[0]) * w3v[0]
              + fast_tanh(acc[rt][1][j] + pp[1]) * w3v[1];
      v += __shfl_xor(v, 1);
      v += __shfl_xor(v, 2);
      v += __shfl_xor(v, 4);
      v += __shfl_xor(v, 8);
      if (l15 == 0) lds_part[wid][rt * 16 + g * 4 + j] = v;
    }
  }
  __syncthreads();

  if (t < R_) {
    float s = 0.f;
    #pragma unroll
    for (int w = 0; w < 8; ++w) s += lds_part[w][t];
    sp[((size_t)b * 2 + slice) * R_ + t] = s;
  }
}

// softmax + weighted sum: grid = B*4, 256 thr, 512 f per block
__global__ __launch_bounds__(256) void wsum_k(const float* __restrict__ feat,
                                              const float* __restrict__ sp,
                                              float* __restrict__ out) {
  int b = blockIdx.x >> 2;
  int f0 = (blockIdx.x & 3) * 512;
  int t = threadIdx.x;
  __shared__ float lds_aw[R_];

  if (t < R_) {
    float s = sp[((size_t)b * 2 + 0) * R_ + t] + sp[((size_t)b * 2 + 1) * R_ + t];
    float m = s;
    #pragma unroll
    for (int off = 32; off >= 1; off >>= 1) m = fmaxf(m, __shfl_xor(m, off));
    float e = __expf(s - m);
    float su = e;
    #pragma unroll
    for (int off = 32; off >= 1; off >>= 1) su += __shfl_xor(su, off);
    lds_aw[t] = e / su;
  }
  __syncthreads();

  const float* fp = feat + (size_t)b * R_ * F_ + f0 + t * 2;
  float qx = 0.f, qy = 0.f;
  #pragma unroll 8
  for (int r = 0; r < R_; ++r) {
    float a = lds_aw[r];
    float2 v = *reinterpret_cast<const float2*>(fp + (size_t)r * F_);
    qx += a * v.x;
    qy += a * v.y;
  }
  *reinterpret_cast<float2*>(out + (size_t)b * F_ + f0 + t * 2) = (float2){qx, qy};
}

extern "C" void kernel_launch(void* const* d_in, const int* in_sizes, int n_in,
                              void* d_out, int out_size, void* d_ws, size_t ws_size,
                              hipStream_t stream) {
  const float* feat = (const float*)d_in[0];   // [B,R,F]
  const float* prev = (const float*)d_in[1];   // [B,H]
  const float* Ww   = (const float*)d_in[2];   // [F,DIM]
  const float* Wb   = (const float*)d_in[3];   // [DIM]
  const float* W2w  = (const float*)d_in[4];   // [H,DIM]
  const float* W2b  = (const float*)d_in[5];   // [DIM]
  const float* W3w  = (const float*)d_in[6];   // [DIM,1]
  // d_in[7] = W3_b: cancels in softmax
  float* out = (float*)d_out;

  ushort* wpack  = (ushort*)d_ws;                                          // 2 MB
  float*  pprime = (float*)((char*)d_ws + (size_t)F_ * DIM_ * 2);          // 512 KB
  float*  sp     = (float*)((char*)d_ws + (size_t)F_ * DIM_ * 2
                                        + (size_t)B_ * DIM_ * 4);          // 128 KB

  setup_k<<<4096 + 256, 256, 0, stream>>>(Ww, wpack, prev, W2w, W2b, Wb, pprime);
  score_k<<<B_ * 2, 512, 0, stream>>>(feat, wpack, pprime, W3w, sp);
  wsum_k<<<B_ * 4, 256, 0, stream>>>(feat, sp, out);
}

// Round 13
// 103.949 us; speedup vs baseline: 1.6867x; 1.1321x over previous
//
#include <hip/hip_runtime.h>
#include <hip/hip_bf16.h>

// attention_84464826843938: additive-attention pooling, MI355X (gfx950)
//
// R13: cut LDS traffic 2.8x. R10 accounting: per-CU-step LDS ~2600cyc
// (16 waves x 8KB frg re-read [8x redundancy: wave owns 32 cols] + raw ring)
// + L2 1700 + MFMA 620 ~= measured 6100. Fix:
//  - wave = 64r x 64c (acc 4x4, 32 MFMA/step): A-frag redundancy 8x -> 4x
//  - no DMA raw ring: direct reg-stage A (4 float4/thread, 2 steps ahead,
//    alternating named sets) -> cvt -> ds_write (frg[kc*64+(row^kc)], R12's
//    verified-0-conflict pattern)
//  - R10's proven schedule: 1 barrier/step, B sets bA/bB alternating via x2
//    unroll, counted vmcnt (steady queue A+1:4,B:8,B+1:8,A+2:4 -> vmcnt(12),
//    tails 8/0), setprio around MFMA.
//  Geometry: BM=64 BN=256 BK=64, 256thr/4waves, grid 512 slice-major, 2 blk/CU.

#define B_ 256
#define R_ 64
#define F_ 2048
#define H_ 512
#define DIM_ 512

typedef short bf16x8 __attribute__((ext_vector_type(8)));
typedef float f32x4 __attribute__((ext_vector_type(4)));

__device__ __forceinline__ ushort f2bf(float x) {
  __hip_bfloat16 h = __float2bfloat16(x);
  return __builtin_bit_cast(ushort, h);
}

__device__ __forceinline__ uint2 pack4(float4 x) {
  uint2 r;
  r.x = (uint)f2bf(x.x) | ((uint)f2bf(x.y) << 16);
  r.y = (uint)f2bf(x.z) | ((uint)f2bf(x.w) << 16);
  return r;
}

// blocks [0,4096): wpack[((kt*32+ctg)*64 + g*16 + c)*8 + i] = bf16(W_w[kt*32+g*8+i][ctg*16+c])
// blocks [4096,4352): p'[b][d] = prev[b]@W2_w[:,d] + W2_b[d] + W_b[d]
__global__ __launch_bounds__(256) void setup_k(const float* __restrict__ Ww,
                                               ushort* __restrict__ wpack,
                                               const float* __restrict__ prev,
                                               const float* __restrict__ W2w,
                                               const float* __restrict__ W2b,
                                               const float* __restrict__ Wb,
                                               float* __restrict__ pprime) {
  __shared__ float lprev[8][H_];
  if (blockIdx.x < 4096) {
    int idx = blockIdx.x * 256 + threadIdx.x;
    float v = Ww[idx];
    int k = idx >> 9;
    int d = idx & 511;
    int kt = k >> 5, kr = k & 31;
    int g = kr >> 3, i = kr & 7;
    int ctg = d >> 4, c = d & 15;
    size_t dst = ((size_t)((kt * 32 + ctg) * 64 + g * 16 + c)) * 8 + (size_t)i;
    wpack[dst] = f2bf(v);
    return;
  }
  int pb = blockIdx.x - 4096;
  int bg = pb >> 3;
  int d0 = (pb & 7) * 64;
  int t = threadIdx.x;
  const float4* src = reinterpret_cast<const float4*>(prev + (size_t)bg * 8 * H_);
  float4* dst = reinterpret_cast<float4*>(&lprev[0][0]);
  for (int i = t; i < 8 * H_ / 4; i += 256) dst[i] = src[i];
  __syncthreads();
  int d = d0 + (t & 63);
  int bq = t >> 6;
  float a0 = 0.f, a1 = 0.f;
  #pragma unroll 8
  for (int h = 0; h < H_; ++h) {
    float wv = W2w[h * DIM_ + d];
    a0 += lprev[bq][h] * wv;
    a1 += lprev[bq + 4][h] * wv;
  }
  float bias = W2b[d] + Wb[d];
  pprime[(size_t)(bg * 8 + bq) * DIM_ + d] = a0 + bias;
  pprime[(size_t)(bg * 8 + bq + 4) * DIM_ + d] = a1 + bias;
}

__device__ __forceinline__ float fast_tanh(float x) {
  float e = __expf(2.f * x);
  return 1.f - 2.f / (e + 1.f);
}

// sp[b*2+slice][r] = sum_{d in slice's 256 cols} tanh(c[b][r][d]+p'[b][d])*W3[d]
__global__ __launch_bounds__(256, 2) void score_k(const float* __restrict__ feat,
                                                  const ushort* __restrict__ wpack,
                                                  const float* __restrict__ pprime,
                                                  const float* __restrict__ W3,
                                                  float* __restrict__ sp) {
  int slice = blockIdx.x >> 8;          // slice-major: both slices of b same XCD
  int b = blockIdx.x & 255;
  int t = threadIdx.x;
  int wid = t >> 6;                     // 4 waves; wave owns cols [wid*64,+64)
  int l = t & 63;
  int l15 = l & 15, g = l >> 4;
  const float* featB = feat + (size_t)b * R_ * F_;

  // frg[buf][kc*64 + (row ^ kc)] = bf16 A[row][k = kt*64 + kc*8 .. +8]
  __shared__ uint4 frg[2][512];         // 2 x 8 KB double buffer
  __shared__ float lds_part[4][R_];

  f32x4 acc[4][4];
  #pragma unroll
  for (int rt = 0; rt < 4; ++rt)
    #pragma unroll
    for (int ct = 0; ct < 4; ++ct)
      acc[rt][ct] = (f32x4){0.f, 0.f, 0.f, 0.f};

  // ---- A staging: thread t covers float4-chunk c4 = t&15 of rows (t>>4)+16j
  int c4 = t & 15;
  int r16 = t >> 4;
  int kcw = c4 >> 1, half = c4 & 1;
  const float* gaj[4];
  int wij[4];
  #pragma unroll
  for (int j = 0; j < 4; ++j) {
    int r = r16 + 16 * j;
    gaj[j] = featB + (size_t)r * F_ + (size_t)(c4 * 4);
    wij[j] = kcw * 64 + (r ^ kcw);
  }

  // ---- B pointer: frag(kt,s,ct) at wp + kt*32768 + s*16384 + ct*512 (ushorts)
  const ushort* wp = wpack + (size_t)(slice * 16 + wid * 4) * 512 + (size_t)l * 8;

#define LOADA(SET, kt) do {                                          \
    _Pragma("unroll")                                                \
    for (int j_ = 0; j_ < 4; ++j_)                                   \
      SET[j_] = *reinterpret_cast<const float4*>(gaj[j_] + (size_t)(kt) * 64); \
  } while (0)

#define CVTW(SET, fb) do {                                           \
    _Pragma("unroll")                                                \
    for (int j_ = 0; j_ < 4; ++j_) {                                 \
      uint2* d_ = reinterpret_cast<uint2*>(&frg[fb][wij[j_]]);       \
      d_[half] = pack4(SET[j_]);                                     \
    }                                                                \
  } while (0)

#define LOADB(dst, kt) do {                                          \
    const ushort* wpk_ = wp + (size_t)(kt) * 32768;                  \
    _Pragma("unroll")                                                \
    for (int s_ = 0; s_ < 2; ++s_)                                   \
      _Pragma("unroll")                                              \
      for (int ct_ = 0; ct_ < 4; ++ct_)                              \
        dst[s_][ct_] = *reinterpret_cast<const uint4*>(              \
            wpk_ + s_ * 16384 + ct_ * 512);                          \
  } while (0)

#define MFMA_STEP(fb, BSET) do {                                     \
    _Pragma("unroll")                                                \
    for (int s_ = 0; s_ < 2; ++s_) {                                 \
      int kc_ = s_ * 4 + g;                                          \
      bf16x8 af_[4];                                                 \
      _Pragma("unroll")                                              \
      for (int rt_ = 0; rt_ < 4; ++rt_)                              \
        af_[rt_] = __builtin_bit_cast(bf16x8,                        \
            frg[fb][kc_ * 64 + ((rt_ * 16 + l15) ^ kc_)]);           \
      _Pragma("unroll")                                              \
      for (int ct_ = 0; ct_ < 4; ++ct_) {                            \
        bf16x8 bv_ = __builtin_bit_cast(bf16x8, BSET[s_][ct_]);      \
        _Pragma("unroll")                                            \
        for (int rt_ = 0; rt_ < 4; ++rt_)                            \
          acc[rt_][ct_] = __builtin_amdgcn_mfma_f32_16x16x32_bf16(   \
              af_[rt_], bv_, acc[rt_][ct_], 0, 0, 0);                \
      }                                                              \
    }                                                                \
  } while (0)

#define WAITBAR(N) do {                                              \
    asm volatile("s_waitcnt vmcnt(" #N ") lgkmcnt(0)" ::: "memory"); \
    __builtin_amdgcn_s_barrier();                                    \
    asm volatile("" ::: "memory");                                   \
  } while (0)

  float4 aS0[4], aS1[4];
  uint4 bA[2][2 * 2], bB[2][2 * 2];     // [s][ct] flattened as [2][4]

  // prologue: A(0)->aS0, B(0)->bA, A(1)->aS1; drain A(0); cvt -> frg[0]
  LOADA(aS0, 0);
  LOADB(bA, 0);
  LOADA(aS1, 1);
  asm volatile("s_waitcnt vmcnt(12)" ::: "memory");
  CVTW(aS0, 0);

  // steady x2-unrolled loop: kt = 0,2,..,26 (even half then odd half)
  for (int kt = 0; kt < 28; kt += 2) {
    // even half (tile kt): frg[0], bA
    LOADB(bB, kt + 1);
    LOADA(aS0, kt + 2);
    WAITBAR(12);
    CVTW(aS1, 1);                       // A(kt+1) -> frg[1]
    __builtin_amdgcn_s_setprio(1);
    MFMA_STEP(0, bA);
    __builtin_amdgcn_s_setprio(0);
    // odd half (tile kt+1): frg[1], bB
    LOADB(bA, kt + 2);
    LOADA(aS1, kt + 3);
    WAITBAR(12);
    CVTW(aS0, 0);                       // A(kt+2) -> frg[0]
    __builtin_amdgcn_s_setprio(1);
    MFMA_STEP(1, bB);
    __builtin_amdgcn_s_setprio(0);
  }
  // peel kt=28..31
  LOADB(bB, 29);
  LOADA(aS0, 30);
  WAITBAR(12);
  CVTW(aS1, 1);
  __builtin_amdgcn_s_setprio(1);
  MFMA_STEP(0, bA);
  __builtin_amdgcn_s_setprio(0);

  LOADB(bA, 30);
  LOADA(aS1, 31);
  WAITBAR(12);
  CVTW(aS0, 0);
  __builtin_amdgcn_s_setprio(1);
  MFMA_STEP(1, bB);
  __builtin_amdgcn_s_setprio(0);

  LOADB(bB, 31);
  WAITBAR(8);                           // queue: A(31):4, B(30):8, B(31):8
  CVTW(aS1, 1);
  __builtin_amdgcn_s_setprio(1);
  MFMA_STEP(0, bA);
  __builtin_amdgcn_s_setprio(0);

  WAITBAR(0);
  __builtin_amdgcn_s_setprio(1);
  MFMA_STEP(1, bB);
  __builtin_amdgcn_s_setprio(0);

#undef LOADA
#undef CVTW
#undef LOADB
#undef MFMA_STEP
#undef WAITBAR

  // epilogue: tanh + W3 dot in registers
  // acc[rt][ct][j] = c[row = rt*16 + g*4 + j][col = slice*256 + wid*64 + ct*16 + l15]
  float pp[4], w3v[4];
  #pragma unroll
  for (int ct = 0; ct < 4; ++ct) {
    int col = slice * 256 + wid * 64 + ct * 16 + l15;
    pp[ct] = pprime[b * DIM_ + col];
    w3v[ct] = W3[col];
  }
  #pragma unroll
  for (int rt = 0; rt < 4; ++rt) {
    #pragma unroll
    for (int j = 0; j < 4; ++j) {
      float v = fast_tanh(acc[rt][0][j] + pp[0]) * w3v[0]
              + fast_tanh(acc[rt][1][j] + pp[1]) * w3v[1]
              + fast_tanh(acc[rt][2][j] + pp[2]) * w3v[2]
              + fast_tanh(acc[rt][3][j] + pp[3]) * w3v[3];
      v += __shfl_xor(v, 1);
      v += __shfl_xor(v, 2);
      v += __shfl_xor(v, 4);
      v += __shfl_xor(v, 8);
      if (l15 == 0) lds_part[wid][rt * 16 + g * 4 + j] = v;
    }
  }
  __syncthreads();

  if (t < R_) {
    float s = lds_part[0][t] + lds_part[1][t] + lds_part[2][t] + lds_part[3][t];
    sp[((size_t)b * 2 + slice) * R_ + t] = s;
  }
}

// softmax + weighted sum: grid = B*4, 256 thr, 512 f per block
__global__ __launch_bounds__(256) void wsum_k(const float* __restrict__ feat,
                                              const float* __restrict__ sp,
                                              float* __restrict__ out) {
  int b = blockIdx.x >> 2;
  int f0 = (blockIdx.x & 3) * 512;
  int t = threadIdx.x;
  __shared__ float lds_aw[R_];

  if (t < R_) {
    float s = sp[((size_t)b * 2 + 0) * R_ + t] + sp[((size_t)b * 2 + 1) * R_ + t];
    float m = s;
    #pragma unroll
    for (int off = 32; off >= 1; off >>= 1) m = fmaxf(m, __shfl_xor(m, off));
    float e = __expf(s - m);
    float su = e;
    #pragma unroll
    for (int off = 32; off >= 1; off >>= 1) su += __shfl_xor(su, off);
    lds_aw[t] = e / su;
  }
  __syncthreads();

  const float* fp = feat + (size_t)b * R_ * F_ + f0 + t * 2;
  float qx = 0.f, qy = 0.f;
  #pragma unroll 8
  for (int r = 0; r < R_; ++r) {
    float a = lds_aw[r];
    float2 v = *reinterpret_cast<const float2*>(fp + (size_t)r * F_);
    qx += a * v.x;
    qy += a * v.y;
  }
  *reinterpret_cast<float2*>(out + (size_t)b * F_ + f0 + t * 2) = (float2){qx, qy};
}

extern "C" void kernel_launch(void* const* d_in, const int* in_sizes, int n_in,
                              void* d_out, int out_size, void* d_ws, size_t ws_size,
                              hipStream_t stream) {
  const float* feat = (const float*)d_in[0];   // [B,R,F]
  const float* prev = (const float*)d_in[1];   // [B,H]
  const float* Ww   = (const float*)d_in[2];   // [F,DIM]
  const float* Wb   = (const float*)d_in[3];   // [DIM]
  const float* W2w  = (const float*)d_in[4];   // [H,DIM]
  const float* W2b  = (const float*)d_in[5];   // [DIM]
  const float* W3w  = (const float*)d_in[6];   // [DIM,1]
  // d_in[7] = W3_b: cancels in softmax
  float* out = (float*)d_out;

  ushort* wpack  = (ushort*)d_ws;                                          // 2 MB
  float*  pprime = (float*)((char*)d_ws + (size_t)F_ * DIM_ * 2);          // 512 KB
  float*  sp     = (float*)((char*)d_ws + (size_t)F_ * DIM_ * 2
                                        + (size_t)B_ * DIM_ * 4);          // 128 KB

  setup_k<<<4096 + 256, 256, 0, stream>>>(Ww, wpack, prev, W2w, W2b, Wb, pprime);
  score_k<<<B_ * 2, 256, 0, stream>>>(feat, wpack, pprime, W3w, sp);
  wsum_k<<<B_ * 4, 256, 0, stream>>>(feat, sp, out);
}